// Round 6
// baseline (835.613 us; speedup 1.0000x reference)
//
#include <hip/hip_runtime.h>

#define DIM 512
#define NROWS 131072

typedef __attribute__((ext_vector_type(8))) __bf16 bf16x8;
typedef __attribute__((ext_vector_type(4))) float f32x4;

__device__ __forceinline__ unsigned short f2bf(float f) {
  unsigned u = __builtin_bit_cast(unsigned, f);
  return (unsigned short)((u + 0x7FFFu + ((u >> 16) & 1u)) >> 16);
}
__device__ __forceinline__ float bf2f(unsigned short u) {
  return __builtin_bit_cast(float, (unsigned)u << 16);
}

__device__ __forceinline__ f32x4 mfma16(bf16x8 a, bf16x8 b, f32x4 c) {
  return __builtin_amdgcn_mfma_f32_16x16x32_bf16(a, b, c, 0, 0, 0);
}

__device__ __forceinline__ float sigmoid_fast(float v) {
  return 1.0f / (1.0f + __expf(-v));
}
__device__ __forceinline__ float tanh_fast(float v) {
  float e = __expf(2.0f * v);
  return 1.0f - 2.0f / (e + 1.0f);
}

__device__ __forceinline__ void gl2lds(const void* g, void* l) {
  __builtin_amdgcn_global_load_lds(
      (const __attribute__((address_space(1))) unsigned int*)g,
      (__attribute__((address_space(3))) unsigned int*)l, 16, 0, 0);
}

// ---------------------------------------------------------------------------
// Weight pre-pack: fp32 W[out=512][in=512] -> bf16 B-fragments.
// Frag (gate g, kstep f, colfrag c): lane l holds 8 bf16 =
//   W[c*16 + (l&15)][f*32 + (l>>4)*8 + 0..7]
// elem index = ((g*16+f)*32 + c)*512 + l*8 + e.  Gates: rx,zx,rh,zh,nx,nh.
// ---------------------------------------------------------------------------
__global__ void prepack_weights(const float* __restrict__ W0, const float* __restrict__ W1,
                                const float* __restrict__ W2, const float* __restrict__ W3,
                                const float* __restrict__ W4, const float* __restrict__ W5,
                                unsigned short* __restrict__ out) {
  int idx = blockIdx.x * 256 + threadIdx.x;
  int e = idx & 7;
  int l = (idx >> 3) & 63;
  int c = (idx >> 9) & 31;
  int f = (idx >> 14) & 15;
  int g = idx >> 18;
  const float* W = (g == 0) ? W0 : (g == 1) ? W1 : (g == 2) ? W2
                 : (g == 3) ? W3 : (g == 4) ? W4 : W5;
  int row = c * 16 + (l & 15);
  int kk  = f * 32 + ((l >> 4) << 3) + e;
  out[idx] = f2bf(W[row * DIM + kk]);
}

// x -> bf16 row-major (async gl2lds A-staging source)
__global__ void prep_x(const float* __restrict__ x, unsigned short* __restrict__ xb) {
  size_t i = (size_t)(blockIdx.x * 256 + threadIdx.x) * 8;
  float4 a0 = *(const float4*)(x + i);
  float4 a1 = *(const float4*)(x + i + 4);
  union { unsigned short us[8]; uint4 v; } p;
  p.us[0] = f2bf(a0.x); p.us[1] = f2bf(a0.y); p.us[2] = f2bf(a0.z); p.us[3] = f2bf(a0.w);
  p.us[4] = f2bf(a1.x); p.us[5] = f2bf(a1.y); p.us[6] = f2bf(a1.z); p.us[7] = f2bf(a1.w);
  *(uint4*)(xb + i) = p.v;
}

// h -> bf16 frag-panel layout: hfb[panel][f16][rf4][lane64][8]
//   row = panel*64 + rf*16 + (lane&15), k = f*32 + (lane>>4)*8 + e
__global__ void prep_h(const float* __restrict__ h, unsigned short* __restrict__ hfb) {
  size_t idx  = (size_t)(blockIdx.x * 256 + threadIdx.x);
  size_t base = idx * 8;
  size_t panel = base >> 15;
  int rem  = (int)(base & 32767);
  int f    = rem >> 11;
  int rf   = (rem >> 9) & 3;
  int lane = (rem >> 3) & 63;
  int row  = (int)panel * 64 + rf * 16 + (lane & 15);
  int k    = f * 32 + (lane >> 4) * 8;
  const float* src = h + (size_t)row * DIM + k;
  float4 a0 = *(const float4*)src;
  float4 a1 = *(const float4*)(src + 4);
  union { unsigned short us[8]; uint4 v; } p;
  p.us[0] = f2bf(a0.x); p.us[1] = f2bf(a0.y); p.us[2] = f2bf(a0.z); p.us[3] = f2bf(a0.w);
  p.us[4] = f2bf(a1.x); p.us[5] = f2bf(a1.y); p.us[6] = f2bf(a1.z); p.us[7] = f2bf(a1.w);
  *(uint4*)(hfb + base) = p.v;
}

// LDS map (bytes):
//   [0, 64K)       sweep1: h frags [f16][rf4][lane][16B]; sweep2: B dbuf 2x32K
//   [64K, 128K)    sweep1: B dbuf 2x32K; after r-epilogue: rh frags
//   [128K, 144K)   x dbuf 2x8K  [pair][f&1][rf4][lane][16B]
#define BOFF 65536
#define XOFF 131072
#define LDS_BYTES 147456

// ---------------------------------------------------------------------------
// Fused GRU, one __syncthreads per window (= vmcnt(0)+lgkm(0)+barrier; stage
// loads get the full MFMA shadow) + A-fragments double-buffered in registers
// (hoisted one window ahead; x frags shared by rx/zx, h frags by rh/zh).
// Block = 64r x 512c, 8 waves, wave = 64r x 64c, 16 MFMA / window.
// ---------------------------------------------------------------------------
__global__ __launch_bounds__(512, 1)
void gru_fused(const float* __restrict__ x, const float* __restrict__ h,
               const unsigned short* __restrict__ xb,
               const unsigned short* __restrict__ hfb,   // frag-panel bf16 h (or null)
               const unsigned char* __restrict__ WB,
               const float* __restrict__ b_rx, const float* __restrict__ b_rh,
               const float* __restrict__ b_zx, const float* __restrict__ b_zh,
               const float* __restrict__ b_nx, const float* __restrict__ b_nh,
               float* __restrict__ out) {
  __shared__ __align__(1024) unsigned char lds[LDS_BYTES];

  const int tid  = threadIdx.x;
  const int lane = tid & 63;
  const int w    = tid >> 6;
  const int cfg0 = w * 4;
  const int row0 = blockIdx.x * 64;
  const int lr   = lane & 15;
  const int lk   = lane >> 4;

  auto stageB = [&](int g, int f, int dst) {   // 32KB chunk, 4 gl2lds/thread
    const unsigned char* src = WB + (size_t)(g * 16 + f) * 32768;
#pragma unroll
    for (int it = 0; it < 4; ++it) {
      int o = (it * 512 + tid) * 16;
      gl2lds(src + o, &lds[dst + o]);
    }
  };
  auto stageXpair = [&](int p) {               // 8KB: k-steps {2p,2p+1}
    int fh = tid >> 8, rf = (tid >> 6) & 3, l = tid & 63;
    const unsigned short* src = xb + (size_t)(row0 + rf * 16 + (l & 15)) * DIM
                                + p * 64 + fh * 32 + (l >> 4) * 8;
    gl2lds(src, &lds[XOFF + (p & 1) * 8192 + tid * 16]);
  };
  auto readA = [&](int abase, bf16x8 (&af)[4]) {
#pragma unroll
    for (int rf = 0; rf < 4; ++rf)
      af[rf] = *(const bf16x8*)&lds[abase + rf * 1024 + lane * 16];
  };
  auto readB = [&](int bbase, bf16x8 (&bfr)[4]) {
#pragma unroll
    for (int cf = 0; cf < 4; ++cf)
      bfr[cf] = *(const bf16x8*)&lds[bbase + (cfg0 + cf) * 1024 + lane * 16];
  };
  auto domfma = [&](bf16x8 (&af)[4], bf16x8 (&bfr)[4], f32x4 (&A)[4][4]) {
    __builtin_amdgcn_s_setprio(1);
#pragma unroll
    for (int rf = 0; rf < 4; ++rf)
#pragma unroll
      for (int cf = 0; cf < 4; ++cf)
        A[rf][cf] = mfma16(af[rf], bfr[cf], A[rf][cf]);
    __builtin_amdgcn_s_setprio(0);
  };

  f32x4 accR[4][4] = {}, accZ[4][4] = {};
  bf16x8 afx[4], afh[4], bfr[4];

  // ---- prologue ----
  stageB(0, 0, BOFF);                  // rx0 -> b0
  stageXpair(0);
  if (hfb) {                           // h frags via async gl2lds (64KB)
    const unsigned char* src = (const unsigned char*)(hfb + (size_t)blockIdx.x * 32768);
#pragma unroll
    for (int it = 0; it < 8; ++it) {
      int o = (it * 512 + tid) * 16;
      gl2lds(src + o, &lds[o]);
    }
  } else {                             // fallback: fp32 h -> bf16 frag LDS
#pragma unroll
    for (int it = 0; it < 16; ++it) {
      int i = tid + it * 512;
      int row = i >> 7;
      int k = (i & 127) * 4;
      float4 hv4 = *(const float4*)(h + (size_t)(row0 + row) * DIM + k);
      union { unsigned short us[4]; uint2 v; } p;
      p.us[0] = f2bf(hv4.x); p.us[1] = f2bf(hv4.y);
      p.us[2] = f2bf(hv4.z); p.us[3] = f2bf(hv4.w);
      *(uint2*)&lds[(k >> 5) * 4096 + (row >> 4) * 1024
                    + (((k >> 3) & 3) * 16 + (row & 15)) * 16 + (k & 4) * 2] = p.v;
    }
  }
  __syncthreads();
  readA(XOFF, afx);                    // x(0)

  // ---- sweep 1: f x {rx, zx, rh, zh}; 1 syncthreads per window ----
#pragma unroll 1
  for (int f = 0; f < 16; ++f) {
    // W0: compute rx(f)@b0; stage zx(f)->b1
    stageB(1, f, BOFF + 32768);
    readB(BOFF, bfr);
    domfma(afx, bfr, accR);
    __syncthreads();
    // W1: compute zx(f)@b1; stage rh(f)->b0; hoist h(f) frags
    stageB(2, f, BOFF);
    readB(BOFF + 32768, bfr);
    readA(f * 4096, afh);
    domfma(afx, bfr, accZ);
    __syncthreads();
    // W2: compute rh(f)@b0; stage zh(f)->b1
    stageB(3, f, BOFF + 32768);
    readB(BOFF, bfr);
    domfma(afh, bfr, accR);
    __syncthreads();
    // W3: compute zh(f)@b1; stage rx(f+1)->b0 (+x pair); hoist x(f+1)
    if (f < 15) {
      stageB(0, f + 1, BOFF);
      if (!(f & 1) && f < 14) stageXpair((f >> 1) + 1);
    }
    readB(BOFF + 32768, bfr);
    if (f < 15) {
      int fn = f + 1;
      readA(XOFF + ((fn >> 1) & 1) * 8192 + (fn & 1) * 4096, afx);
    }
    domfma(afh, bfr, accZ);
    __syncthreads();
  }

  // ---- r-epilogue: r = sigmoid(accR+b); rh = r*h -> frag LDS @BOFF ----
#pragma unroll
  for (int cf = 0; cf < 4; ++cf) {
    const int col  = (cfg0 + cf) * 16 + lr;
    const float bs = b_rx[col] + b_rh[col];
    const int fcol  = col >> 5;
    const int l2b   = ((col >> 3) & 3) * 16;
    const int ebyte = (col & 7) * 2;
#pragma unroll
    for (int rf = 0; rf < 4; ++rf) {
#pragma unroll
      for (int j = 0; j < 4; ++j) {
        const int rsub = lk * 4 + j;
        unsigned short hu = *(const unsigned short*)
            &lds[fcol * 4096 + rf * 1024 + (l2b + rsub) * 16 + ebyte];
        float rv = sigmoid_fast(accR[rf][cf][j] + bs);
        *(unsigned short*)
            &lds[BOFF + fcol * 4096 + rf * 1024 + (l2b + rsub) * 16 + ebyte]
            = f2bf(rv * bf2f(hu));
      }
    }
  }
  __syncthreads();                     // rh visible; h-frag region now dead

  // ---- sweep 2: f x {nx, nh}; B dbuf @[0,64K); A(nh)=rh frags @BOFF ----
  f32x4 accN[4][4] = {};
  stageB(4, 0, 0);                     // nx0 -> c0
  stageXpair(0);
  __syncthreads();
  readA(XOFF, afx);
#pragma unroll 1
  for (int f = 0; f < 16; ++f) {
    // V0: compute nx(f)@c0; stage nh(f)->c1; hoist rh(f)
    stageB(5, f, 32768);
    readB(0, bfr);
    readA(BOFF + f * 4096, afh);       // rh frags
    domfma(afx, bfr, accN);
    __syncthreads();
    // V1: compute nh(f)@c1; stage nx(f+1)->c0 (+x pair); hoist x(f+1)
    if (f < 15) {
      stageB(4, f + 1, 0);
      if (!(f & 1) && f < 14) stageXpair((f >> 1) + 1);
    }
    readB(32768, bfr);
    if (f < 15) {
      int fn = f + 1;
      readA(XOFF + ((fn >> 1) & 1) * 8192 + (fn & 1) * 4096, afx);
    }
    domfma(afh, bfr, accN);
    __syncthreads();
  }

  // ---- final epilogue: n = tanh(accN+b), z = sigmoid(accZ+b), combine ----
#pragma unroll
  for (int cf = 0; cf < 4; ++cf) {
    const int col  = (cfg0 + cf) * 16 + lr;
    const float bn = b_nx[col] + b_nh[col];
    const float bz = b_zx[col] + b_zh[col];
#pragma unroll
    for (int rf = 0; rf < 4; ++rf) {
#pragma unroll
      for (int j = 0; j < 4; ++j) {
        const int row = rf * 16 + lk * 4 + j;
        const size_t off = (size_t)(row0 + row) * DIM + col;
        float hv = h[off];
        float nv = tanh_fast(accN[rf][cf][j] + bn);
        float zv = sigmoid_fast(accZ[rf][cf][j] + bz);
        out[off] = (1.0f - zv) * nv + zv * hv;
      }
    }
  }
}

extern "C" void kernel_launch(void* const* d_in, const int* in_sizes, int n_in,
                              void* d_out, int out_size, void* d_ws, size_t ws_size,
                              hipStream_t stream) {
  const float* x    = (const float*)d_in[0];
  const float* h    = (const float*)d_in[1];
  const float* W_rx = (const float*)d_in[2];
  const float* b_rx = (const float*)d_in[3];
  const float* W_rh = (const float*)d_in[4];
  const float* b_rh = (const float*)d_in[5];
  const float* W_zx = (const float*)d_in[6];
  const float* b_zx = (const float*)d_in[7];
  const float* W_zh = (const float*)d_in[8];
  const float* b_zh = (const float*)d_in[9];
  const float* W_nx = (const float*)d_in[10];
  const float* b_nx = (const float*)d_in[11];
  const float* W_nh = (const float*)d_in[12];
  const float* b_nh = (const float*)d_in[13];

  unsigned char* ws = (unsigned char*)d_ws;
  unsigned short* wpack = (unsigned short*)ws;                  // 3 MiB
  unsigned short* xb    = (unsigned short*)(ws + (4ull << 20)); // 128 MiB
  const size_t hfb_off  = (4ull << 20) + (size_t)NROWS * DIM * 2;
  const size_t need_h   = hfb_off + (size_t)NROWS * DIM * 2;
  unsigned short* hfb   = (ws_size >= need_h) ? (unsigned short*)(ws + hfb_off)
                                              : (unsigned short*)nullptr;

  // gate order: rx, zx, rh, zh, nx, nh
  prepack_weights<<<6144, 256, 0, stream>>>(W_rx, W_zx, W_rh, W_zh, W_nx, W_nh, wpack);
  prep_x<<<32768, 256, 0, stream>>>(x, xb);
  if (hfb) prep_h<<<32768, 256, 0, stream>>>(h, hfb);
  gru_fused<<<NROWS / 64, 512, 0, stream>>>(x, h, xb, hfb,
                                            (const unsigned char*)wpack,
                                            b_rx, b_rh, b_zx, b_zh, b_nx, b_nh,
                                            (float*)d_out);
}

// Round 7
// 726.212 us; speedup vs baseline: 1.1506x; 1.1506x over previous
//
#include <hip/hip_runtime.h>

#define DIM 512
#define NROWS 131072

typedef __attribute__((ext_vector_type(8))) __bf16 bf16x8;
typedef __attribute__((ext_vector_type(4))) float f32x4;

__device__ __forceinline__ unsigned short f2bf(float f) {
  unsigned u = __builtin_bit_cast(unsigned, f);
  return (unsigned short)((u + 0x7FFFu + ((u >> 16) & 1u)) >> 16);
}
__device__ __forceinline__ float bf2f(unsigned short u) {
  return __builtin_bit_cast(float, (unsigned)u << 16);
}

__device__ __forceinline__ f32x4 mfma16(bf16x8 a, bf16x8 b, f32x4 c) {
  return __builtin_amdgcn_mfma_f32_16x16x32_bf16(a, b, c, 0, 0, 0);
}

__device__ __forceinline__ float sigmoid_fast(float v) {
  return 1.0f / (1.0f + __expf(-v));
}
__device__ __forceinline__ float tanh_fast(float v) {
  float e = __expf(2.0f * v);
  return 1.0f - 2.0f / (e + 1.0f);
}

// ---------------------------------------------------------------------------
// Weight pre-pack: fp32 W[out=512][in=512] -> bf16 B-fragments.
// Frag (gate g, kstep f, colfrag c): lane l holds 8 bf16 =
//   W[c*16 + (l&15)][f*32 + (l>>4)*8 + 0..7]
// elem index = ((g*16+f)*32 + c)*512 + l*8 + e.  Gates: rx,zx,rh,zh,nx,nh.
// ---------------------------------------------------------------------------
__global__ void prepack_weights(const float* __restrict__ W0, const float* __restrict__ W1,
                                const float* __restrict__ W2, const float* __restrict__ W3,
                                const float* __restrict__ W4, const float* __restrict__ W5,
                                unsigned short* __restrict__ out) {
  int idx = blockIdx.x * 256 + threadIdx.x;
  int e = idx & 7;
  int l = (idx >> 3) & 63;
  int c = (idx >> 9) & 31;
  int f = (idx >> 14) & 15;
  int g = idx >> 18;
  const float* W = (g == 0) ? W0 : (g == 1) ? W1 : (g == 2) ? W2
                 : (g == 3) ? W3 : (g == 4) ? W4 : W5;
  int row = c * 16 + (l & 15);
  int kk  = f * 32 + ((l >> 4) << 3) + e;
  out[idx] = f2bf(W[row * DIM + kk]);
}

// x -> bf16 row-major (direct per-lane A-fragment loads in the main kernel)
__global__ void prep_x(const float* __restrict__ x, unsigned short* __restrict__ xb) {
  size_t i = (size_t)(blockIdx.x * 256 + threadIdx.x) * 8;
  float4 a0 = *(const float4*)(x + i);
  float4 a1 = *(const float4*)(x + i + 4);
  union { unsigned short us[8]; uint4 v; } p;
  p.us[0] = f2bf(a0.x); p.us[1] = f2bf(a0.y); p.us[2] = f2bf(a0.z); p.us[3] = f2bf(a0.w);
  p.us[4] = f2bf(a1.x); p.us[5] = f2bf(a1.y); p.us[6] = f2bf(a1.z); p.us[7] = f2bf(a1.w);
  *(uint4*)(xb + i) = p.v;
}

// ---------------------------------------------------------------------------
// Fused GRU, barrier-free register pipeline.
// Block = 64 rows x 512 cols, 8 waves, wave = 64r x 64c, free-running.
// LDS: h frags only (64 KB), overwritten in place by rh at the r-epilogue.
// B-fragments: direct global->reg loads (L2/L3-hot weights), 1-window lead.
// x-fragments: direct global->reg from bf16 row-major xb, 1-iteration lead.
// z lives in accZ registers across the whole kernel; rh lives in LDS.
// Only 3 barriers total (after h-prologue, around the r-epilogue).
// ---------------------------------------------------------------------------
__global__ __launch_bounds__(512, 2)
void gru_fused(const float* __restrict__ h,
               const unsigned short* __restrict__ xb,
               const unsigned char* __restrict__ WB,
               const float* __restrict__ b_rx, const float* __restrict__ b_rh,
               const float* __restrict__ b_zx, const float* __restrict__ b_zh,
               const float* __restrict__ b_nx, const float* __restrict__ b_nh,
               float* __restrict__ out) {
  __shared__ __align__(1024) unsigned char lds[65536];

  const int tid  = threadIdx.x;
  const int lane = tid & 63;
  const int w    = tid >> 6;
  const int row0 = blockIdx.x * 64;
  const int lr   = lane & 15;
  const int lk   = lane >> 4;
  const int boff = w * 4096 + lane * 16;   // wave's byte offset in a 32KB B chunk

  auto loadB = [&](int g, int f, bf16x8 (&b)[4]) {
    const unsigned char* p = WB + (((size_t)(g * 16 + f)) << 15) + boff;
#pragma unroll
    for (int cf = 0; cf < 4; ++cf)
      b[cf] = *(const bf16x8*)(p + cf * 1024);
  };
  auto loadXA = [&](int f, bf16x8 (&a)[4]) {
#pragma unroll
    for (int rf = 0; rf < 4; ++rf)
      a[rf] = *(const bf16x8*)(xb + (size_t)(row0 + rf * 16 + lr) * DIM
                               + f * 32 + lk * 8);
  };
  auto readLDS = [&](int f, bf16x8 (&a)[4]) {
#pragma unroll
    for (int rf = 0; rf < 4; ++rf)
      a[rf] = *(const bf16x8*)&lds[f * 4096 + rf * 1024 + lane * 16];
  };

#define WINDOW(Aset, Bset, ACC)                                                \
  _Pragma("unroll")                                                            \
  for (int rf_ = 0; rf_ < 4; ++rf_)                                            \
    _Pragma("unroll")                                                          \
    for (int cf_ = 0; cf_ < 4; ++cf_)                                          \
      ACC[rf_][cf_] = mfma16(Aset[rf_], Bset[cf_], ACC[rf_][cf_]);

  bf16x8 bA[4], bB[4], xaC[4], xaN[4], ha[4];

  // ---- prologue: prefetch first operands, convert h -> bf16 frag LDS ----
  loadB(0, 0, bA);                     // B_rx(0)
  loadB(1, 0, bB);                     // B_zx(0)
  loadXA(0, xaC);
#pragma unroll
  for (int it = 0; it < 16; ++it) {
    int i = tid + it * 512;
    int row = i >> 7;
    int k = (i & 127) * 4;
    float4 hv4 = *(const float4*)(h + (size_t)(row0 + row) * DIM + k);
    union { unsigned short us[4]; uint2 v; } p;
    p.us[0] = f2bf(hv4.x); p.us[1] = f2bf(hv4.y);
    p.us[2] = f2bf(hv4.z); p.us[3] = f2bf(hv4.w);
    *(uint2*)&lds[(k >> 5) * 4096 + (row >> 4) * 1024
                  + (((k >> 3) & 3) * 16 + (row & 15)) * 16 + (k & 4) * 2] = p.v;
  }
  __syncthreads();                     // h frags visible to all waves

  // ---- sweep 1: f x {rx, zx, rh, zh}; no barriers, reg-dbuf'd B and x ----
  f32x4 accR[4][4] = {}, accZ[4][4] = {};
#pragma unroll 1
  for (int f = 0; f < 16; ++f) {
    const int fn = (f < 15) ? f + 1 : 15;
    readLDS(f, ha);                    // h(f) frags (used 2 windows later)
    // rx(f)
    WINDOW(xaC, bA, accR);
    loadB(2, f, bA);                   // B_rh(f)
    // zx(f)
    WINDOW(xaC, bB, accZ);
    loadB(3, f, bB);                   // B_zh(f)
    loadXA(fn, xaN);                   // x(f+1)
    // rh(f)
    WINDOW(ha, bA, accR);
    loadB(0, fn, bA);                  // B_rx(f+1)
    // zh(f)
    WINDOW(ha, bB, accZ);
    loadB(1, fn, bB);                  // B_zx(f+1)
#pragma unroll
    for (int rf = 0; rf < 4; ++rf) xaC[rf] = xaN[rf];
  }

  // prefetch sweep-2 operands under the epilogue
  loadB(4, 0, bA);                     // B_nx(0)
  loadB(5, 0, bB);                     // B_nh(0)
  loadXA(0, xaC);
  __syncthreads();                     // all waves done reading h frags

  // ---- r-epilogue: rh = sigmoid(accR+b) * h, in place in LDS ----
#pragma unroll
  for (int cf = 0; cf < 4; ++cf) {
    const int col  = (w * 4 + cf) * 16 + lr;
    const float bs = b_rx[col] + b_rh[col];
    const int fcol = col >> 5;
    const int l2b  = ((col >> 3) & 3) * 16;
    const int eb   = (col & 7) * 2;
#pragma unroll
    for (int rf = 0; rf < 4; ++rf) {
#pragma unroll
      for (int j = 0; j < 4; ++j) {
        const int rsub = lk * 4 + j;
        const int addr = fcol * 4096 + rf * 1024 + (l2b + rsub) * 16 + eb;
        unsigned short hu = *(const unsigned short*)&lds[addr];
        float rv = sigmoid_fast(accR[rf][cf][j] + bs);
        *(unsigned short*)&lds[addr] = f2bf(rv * bf2f(hu));
      }
    }
  }
  __syncthreads();                     // rh frags visible

  // ---- sweep 2: f x {nx, nh}; A(nh) = rh frags from LDS ----
  f32x4 accN[4][4] = {};
#pragma unroll 1
  for (int f = 0; f < 16; ++f) {
    const int fn = (f < 15) ? f + 1 : 15;
    readLDS(f, ha);                    // rh(f) frags
    // nx(f)
    WINDOW(xaC, bA, accN);
    loadB(4, fn, bA);                  // B_nx(f+1)
    loadXA(fn, xaN);
    // nh(f)
    WINDOW(ha, bB, accN);
    loadB(5, fn, bB);                  // B_nh(f+1)
#pragma unroll
    for (int rf = 0; rf < 4; ++rf) xaC[rf] = xaN[rf];
  }

  // ---- final epilogue: n = tanh(accN+b), z = sigmoid(accZ+b), combine ----
#pragma unroll
  for (int cf = 0; cf < 4; ++cf) {
    const int col  = (w * 4 + cf) * 16 + lr;
    const float bn = b_nx[col] + b_nh[col];
    const float bz = b_zx[col] + b_zh[col];
#pragma unroll
    for (int rf = 0; rf < 4; ++rf) {
#pragma unroll
      for (int j = 0; j < 4; ++j) {
        const int row = rf * 16 + lk * 4 + j;
        const size_t off = (size_t)(row0 + row) * DIM + col;
        float hv = h[off];
        float nv = tanh_fast(accN[rf][cf][j] + bn);
        float zv = sigmoid_fast(accZ[rf][cf][j] + bz);
        out[off] = (1.0f - zv) * nv + zv * hv;
      }
    }
  }
#undef WINDOW
}

extern "C" void kernel_launch(void* const* d_in, const int* in_sizes, int n_in,
                              void* d_out, int out_size, void* d_ws, size_t ws_size,
                              hipStream_t stream) {
  const float* x    = (const float*)d_in[0];
  const float* h    = (const float*)d_in[1];
  const float* W_rx = (const float*)d_in[2];
  const float* b_rx = (const float*)d_in[3];
  const float* W_rh = (const float*)d_in[4];
  const float* b_rh = (const float*)d_in[5];
  const float* W_zx = (const float*)d_in[6];
  const float* b_zx = (const float*)d_in[7];
  const float* W_zh = (const float*)d_in[8];
  const float* b_zh = (const float*)d_in[9];
  const float* W_nx = (const float*)d_in[10];
  const float* b_nx = (const float*)d_in[11];
  const float* W_nh = (const float*)d_in[12];
  const float* b_nh = (const float*)d_in[13];

  unsigned char* ws = (unsigned char*)d_ws;
  unsigned short* wpack = (unsigned short*)ws;                  // 3 MiB
  unsigned short* xb    = (unsigned short*)(ws + (4ull << 20)); // 128 MiB

  // gate order: rx, zx, rh, zh, nx, nh
  prepack_weights<<<6144, 256, 0, stream>>>(W_rx, W_zx, W_rh, W_zh, W_nx, W_nh, wpack);
  prep_x<<<32768, 256, 0, stream>>>(x, xb);
  gru_fused<<<NROWS / 64, 512, 0, stream>>>(h, xb, (const unsigned char*)wpack,
                                            b_rx, b_rh, b_zx, b_zh, b_nx, b_nh,
                                            (float*)d_out);
}